// Round 1
// baseline (122.843 us; speedup 1.0000x reference)
//
#include <hip/hip_runtime.h>
#include <hip/hip_bf16.h>

using short8  = __attribute__((ext_vector_type(8))) short;   // 8 bf16 (4 VGPRs)
using floatx4 = __attribute__((ext_vector_type(4))) float;   // 4 fp32 acc

#define B_ROWS 4096
#define NTOT   8192
#define DD     128

// ---------------- kernel 1: L2-normalize rows, cast to bf16 ----------------
// one wave per row (2 elements/lane), 4 rows/block
__global__ __launch_bounds__(256) void nrm_kernel(const float* __restrict__ zi,
                                                  const float* __restrict__ zj,
                                                  __hip_bfloat16* __restrict__ zb) {
    int tid  = threadIdx.x;
    int wave = tid >> 6, lane = tid & 63;
    int row  = blockIdx.x * 4 + wave;
    const float* src = (row < B_ROWS) ? (zi + (size_t)row * DD)
                                      : (zj + (size_t)(row - B_ROWS) * DD);
    float2 v = *(const float2*)(src + lane * 2);
    float s = v.x * v.x + v.y * v.y;
    #pragma unroll
    for (int m = 1; m <= 32; m <<= 1) s += __shfl_xor(s, m, 64);
    float scale = 1.0f / fmaxf(sqrtf(s), 1e-12f);
    __hip_bfloat16* dst = zb + (size_t)row * DD + lane * 2;
    dst[0] = __float2bfloat16(v.x * scale);
    dst[1] = __float2bfloat16(v.y * scale);
}

// ---------------- kernel 2: fused sim-GEMM + partial sum-exp ----------------
// grid (128 row-tiles, 4 col-quarters); block 256 = 4 waves x 16 rows.
// Each block: rows [bi*64, bi*64+64), cols [cq*2048, cq*2048+2048).
// l_partial[row][cq] = sum over cols of exp(sim - 2);  p_partial = pos dot.
__global__ __launch_bounds__(256) void sim_kernel(const __hip_bfloat16* __restrict__ zbf,
                                                  float* __restrict__ lpart,
                                                  float* __restrict__ ppart) {
    // B-tile: 64 cols x 128 k bf16 = 16 KB, stored as 16B chunks:
    // addr chunk = [subtile(4)][n(16)][slot(16)], slot = kc8 ^ n  (bank de-conflict)
    __shared__ uint4 ldsB[1024];

    int tid  = threadIdx.x;
    int w    = tid >> 6, lane = tid & 63;
    int q    = lane >> 4, n16 = lane & 15;
    int bi   = blockIdx.x, cq = blockIdx.y;
    int r0   = bi * 64 + w * 16;

    const short* zs = (const short*)zbf;

    // A fragments resident in registers: rows r0..r0+15, full K=128 (4 chunks of 32)
    // A-operand layout: m = lane&15, k = (lane>>4)*8 + j  within each K=32 chunk
    short8 afrag[4];
    int arow = r0 + n16;
    #pragma unroll
    for (int kc = 0; kc < 4; ++kc)
        afrag[kc] = *(const short8*)(zs + (size_t)arow * DD + kc * 32 + q * 8);

    float l[4]  = {0.f, 0.f, 0.f, 0.f};
    float ps[4] = {0.f, 0.f, 0.f, 0.f};
    const float C1 = 2.8853900817779268f; // 2*log2(e): exp(2*dot-2)=2^(dot*C1 - C1)

    for (int t = 0; t < 32; ++t) {
        int j0 = cq * 2048 + t * 64;
        // ---- stage B tile: 1024 16B chunks, coalesced (contiguous 16 KB in global)
        #pragma unroll
        for (int rr = 0; rr < 4; ++rr) {
            int c   = tid + 256 * rr;
            int row = c >> 4, kc8 = c & 15;       // row in [0,64), kc8 = k/8
            int sub = row >> 4, n = row & 15;
            ldsB[sub * 256 + n * 16 + (kc8 ^ n)] =
                *(const uint4*)(zs + (size_t)(j0 + row) * DD + kc8 * 8);
        }
        __syncthreads();
        // ---- 4 sub-tiles of 16 cols; K-loop 4 x (16x16x32 MFMA)
        #pragma unroll
        for (int st = 0; st < 4; ++st) {
            floatx4 acc = {0.f, 0.f, 0.f, 0.f};
            #pragma unroll
            for (int kc = 0; kc < 4; ++kc) {
                short8 bfrag = *(const short8*)&ldsB[st * 256 + n16 * 16 + (((kc << 2) | q) ^ n16)];
                acc = __builtin_amdgcn_mfma_f32_16x16x32_bf16(afrag[kc], bfrag, acc, 0, 0, 0);
            }
            int col = j0 + st * 16 + n16;
            #pragma unroll
            for (int r = 0; r < 4; ++r) {
                float sdot = acc[r];                 // C layout: row = q*4+r, col = n16
                int   row  = r0 + q * 4 + r;
                if (col == (row ^ B_ROWS)) ps[r] = sdot;   // positive pair
                l[r] += __builtin_amdgcn_exp2f(sdot * C1 - C1);
            }
        }
        __syncthreads();
    }

    // reduce the 16 column-lanes (same q group holds the same 4 rows)
    #pragma unroll
    for (int r = 0; r < 4; ++r) {
        #pragma unroll
        for (int m = 1; m < 16; m <<= 1) {
            l[r]  += __shfl_xor(l[r],  m, 64);
            ps[r] += __shfl_xor(ps[r], m, 64);
        }
    }
    if (n16 == 0) {
        #pragma unroll
        for (int r = 0; r < 4; ++r) {
            int row = r0 + q * 4 + r;
            lpart[row * 4 + cq] = l[r];
            ppart[row * 4 + cq] = ps[r];
        }
    }
}

// ---------------- kernel 3: finalize ----------------
// loss_i = -2*pos_dot + 2 + ln(sum_exp - 1);  mean over 8192 rows -> atomicAdd
__global__ __launch_bounds__(256) void fin_kernel(const float* __restrict__ lpart,
                                                  const float* __restrict__ ppart,
                                                  float* __restrict__ out) {
    int row = blockIdx.x * 256 + threadIdx.x;
    float l = lpart[row * 4 + 0] + lpart[row * 4 + 1] +
              lpart[row * 4 + 2] + lpart[row * 4 + 3] - 1.0f;   // -1: diagonal exp(0)
    float p = ppart[row * 4 + 0] + ppart[row * 4 + 1] +
              ppart[row * 4 + 2] + ppart[row * 4 + 3];
    float loss = -2.0f * p + 2.0f + logf(l);
    #pragma unroll
    for (int m = 1; m <= 32; m <<= 1) loss += __shfl_xor(loss, m, 64);
    if ((threadIdx.x & 63) == 0) atomicAdd(out, loss * (1.0f / (float)NTOT));
}

extern "C" void kernel_launch(void* const* d_in, const int* in_sizes, int n_in,
                              void* d_out, int out_size, void* d_ws, size_t ws_size,
                              hipStream_t stream) {
    const float* zi = (const float*)d_in[0];
    const float* zj = (const float*)d_in[1];
    float* out = (float*)d_out;

    __hip_bfloat16* zb = (__hip_bfloat16*)d_ws;                       // 2 MB
    float* lpart = (float*)((char*)d_ws + (size_t)NTOT * DD * 2);     // 128 KB
    float* ppart = lpart + NTOT * 4;                                  // 128 KB

    hipMemsetAsync(d_out, 0, sizeof(float), stream);
    nrm_kernel<<<NTOT / 4, 256, 0, stream>>>(zi, zj, zb);
    sim_kernel<<<dim3(128, 4), 256, 0, stream>>>(zb, lpart, ppart);
    fin_kernel<<<NTOT / 256, 256, 0, stream>>>(lpart, ppart, out);
}

// Round 2
// 91.594 us; speedup vs baseline: 1.3412x; 1.3412x over previous
//
#include <hip/hip_runtime.h>
#include <hip/hip_bf16.h>

using short8  = __attribute__((ext_vector_type(8))) short;   // 8 bf16 (4 VGPRs)
using floatx4 = __attribute__((ext_vector_type(4))) float;   // 4 fp32 acc

#define B_ROWS 4096
#define NTOT   8192
#define DD     128
#define SQRTC1 1.6986436f            // sqrt(2*log2(e)) — pre-scale so MFMA yields C1*dot
#define E2f    7.389056098930650f    // exp(2): diagonal term (self-dot) to subtract
#define LN2f   0.6931471805599453f   // 2p = d' * ln2  (d' = C1 * p)

// ---------------- kernel 1: L2-normalize rows, scale by sqrt(C1), cast bf16 ----------------
__global__ __launch_bounds__(256) void nrm_kernel(const float* __restrict__ zi,
                                                  const float* __restrict__ zj,
                                                  __hip_bfloat16* __restrict__ zb) {
    int tid  = threadIdx.x;
    int wave = tid >> 6, lane = tid & 63;
    int row  = blockIdx.x * 4 + wave;
    const float* src = (row < B_ROWS) ? (zi + (size_t)row * DD)
                                      : (zj + (size_t)(row - B_ROWS) * DD);
    float2 v = *(const float2*)(src + lane * 2);
    float s = v.x * v.x + v.y * v.y;
    #pragma unroll
    for (int m = 1; m <= 32; m <<= 1) s += __shfl_xor(s, m, 64);
    float scale = SQRTC1 / fmaxf(sqrtf(s), 1e-12f);
    __hip_bfloat16* dst = zb + (size_t)row * DD + lane * 2;
    dst[0] = __float2bfloat16(v.x * scale);
    dst[1] = __float2bfloat16(v.y * scale);
}

// ---------------- kernel 2: fused sim-GEMM + partial sum of exp2 ----------------
// grid (32 row-tiles, 32 col-splits); block 256 = 4 waves.
// Block tile: 256 rows x 256 cols. Wave w owns rows [r0+w*64, +64) as 4 row-fragments
// (4x B-reuse per ds_read). t-loop stages 64 cols (16 KB) shared by all 4 waves.
// lpart[row][cs] = sum over cols of exp2(C1*dot)  (includes diagonal, removed later).
__global__ __launch_bounds__(256, 4) void sim_kernel(const __hip_bfloat16* __restrict__ zbf,
                                                     float* __restrict__ lpart) {
    // 64 cols x 128 k bf16 = 16 KB as 16B chunks: addr = col*16 + (kc8 ^ (col&15))
    __shared__ uint4 ldsB[1024];
    const short* zs = (const short*)zbf;

    int tid = threadIdx.x;
    int w   = tid >> 6, lane = tid & 63;
    int q   = lane >> 4, n16 = lane & 15;
    int r0  = blockIdx.x * 256 + w * 64;
    int cq  = blockIdx.y;

    // A fragments: 4 rowsets x full K=128 (4 chunks of 32). 64 VGPRs, resident.
    // A layout: m = lane&15, k = (lane>>4)*8 + j within each K=32 chunk.
    short8 af[4][4];
    #pragma unroll
    for (int rs = 0; rs < 4; ++rs) {
        int arow = r0 + rs * 16 + n16;
        #pragma unroll
        for (int kc = 0; kc < 4; ++kc)
            af[rs][kc] = *(const short8*)(zs + (size_t)arow * DD + kc * 32 + q * 8);
    }

    float l[4][4];
    #pragma unroll
    for (int rs = 0; rs < 4; ++rs)
        #pragma unroll
        for (int r = 0; r < 4; ++r) l[rs][r] = 0.f;

    for (int t = 0; t < 4; ++t) {
        int j0 = cq * 256 + t * 64;
        // ---- stage B tile: 1024 16B chunks, coalesced in global, xor-swizzled in LDS
        #pragma unroll
        for (int rr = 0; rr < 4; ++rr) {
            int c = tid + 256 * rr;
            int col = c >> 4, kc8 = c & 15;
            ldsB[col * 16 + (kc8 ^ (col & 15))] =
                *(const uint4*)(zs + (size_t)(j0 + col) * DD + kc8 * 8);
        }
        __syncthreads();
        // ---- 4 subtiles of 16 cols; per subtile: 4 ds_reads feed 16 MFMAs
        #pragma unroll
        for (int st = 0; st < 4; ++st) {
            floatx4 acc[4];
            #pragma unroll
            for (int rs = 0; rs < 4; ++rs) acc[rs] = (floatx4){0.f, 0.f, 0.f, 0.f};
            #pragma unroll
            for (int kc = 0; kc < 4; ++kc) {
                short8 bf = *(const short8*)&ldsB[(st * 16 + n16) * 16 + (((kc << 2) | q) ^ n16)];
                #pragma unroll
                for (int rs = 0; rs < 4; ++rs)
                    acc[rs] = __builtin_amdgcn_mfma_f32_16x16x32_bf16(af[rs][kc], bf, acc[rs], 0, 0, 0);
            }
            // epilogue: exactly exp2 + add per element (C layout: row=q*4+r, col=n16)
            #pragma unroll
            for (int rs = 0; rs < 4; ++rs)
                #pragma unroll
                for (int r = 0; r < 4; ++r)
                    l[rs][r] += __builtin_amdgcn_exp2f(acc[rs][r]);
        }
        __syncthreads();
    }

    // reduce the 16 column-lanes (lanes sharing q hold the same 4 rows)
    #pragma unroll
    for (int rs = 0; rs < 4; ++rs)
        #pragma unroll
        for (int r = 0; r < 4; ++r) {
            float v = l[rs][r];
            v += __shfl_xor(v, 1, 64);
            v += __shfl_xor(v, 2, 64);
            v += __shfl_xor(v, 4, 64);
            v += __shfl_xor(v, 8, 64);
            l[rs][r] = v;
        }
    if (n16 == 0) {
        #pragma unroll
        for (int rs = 0; rs < 4; ++rs)
            #pragma unroll
            for (int r = 0; r < 4; ++r) {
                int row = r0 + rs * 16 + q * 4 + r;
                lpart[row * 32 + cq] = l[rs][r];
            }
    }
}

// ---------------- kernel 3: finalize ----------------
// loss_i = -d'*ln2 + ln(sum_exp2 - e^2); mean via block reduce + 32 atomics
__global__ __launch_bounds__(256) void fin_kernel(const __hip_bfloat16* __restrict__ zbf,
                                                  const float* __restrict__ lpart,
                                                  float* __restrict__ out) {
    __shared__ float red[256];
    int row = blockIdx.x * 256 + threadIdx.x;

    const float4* lp = (const float4*)(lpart + row * 32);
    float l = 0.f;
    #pragma unroll
    for (int i = 0; i < 8; ++i) { float4 v = lp[i]; l += (v.x + v.y) + (v.z + v.w); }

    const __hip_bfloat162* a = (const __hip_bfloat162*)(zbf + (size_t)row * DD);
    const __hip_bfloat162* b = (const __hip_bfloat162*)(zbf + (size_t)(row ^ B_ROWS) * DD);
    float d = 0.f;
    #pragma unroll
    for (int i = 0; i < 64; ++i) {
        float2 av = __bfloat1622float2(a[i]);
        float2 bv = __bfloat1622float2(b[i]);
        d += av.x * bv.x + av.y * bv.y;
    }

    float loss = -d * LN2f + logf(l - E2f);
    red[threadIdx.x] = loss;
    __syncthreads();
    #pragma unroll
    for (int s = 128; s > 0; s >>= 1) {
        if (threadIdx.x < s) red[threadIdx.x] += red[threadIdx.x + s];
        __syncthreads();
    }
    if (threadIdx.x == 0) atomicAdd(out, red[0] * (1.0f / (float)NTOT));
}

extern "C" void kernel_launch(void* const* d_in, const int* in_sizes, int n_in,
                              void* d_out, int out_size, void* d_ws, size_t ws_size,
                              hipStream_t stream) {
    const float* zi = (const float*)d_in[0];
    const float* zj = (const float*)d_in[1];
    float* out = (float*)d_out;

    __hip_bfloat16* zb = (__hip_bfloat16*)d_ws;                         // 2 MB
    float* lpart = (float*)((char*)d_ws + (size_t)NTOT * DD * 2);       // 1 MB (8192 x 32)

    hipMemsetAsync(d_out, 0, sizeof(float), stream);
    nrm_kernel<<<NTOT / 4, 256, 0, stream>>>(zi, zj, zb);
    sim_kernel<<<dim3(32, 32), 256, 0, stream>>>(zb, lpart);
    fin_kernel<<<NTOT / 256, 256, 0, stream>>>(zb, lpart, out);
}

// Round 3
// 88.400 us; speedup vs baseline: 1.3896x; 1.0361x over previous
//
#include <hip/hip_runtime.h>
#include <hip/hip_bf16.h>

using short8  = __attribute__((ext_vector_type(8))) short;   // 8 bf16 (4 VGPRs)
using floatx4 = __attribute__((ext_vector_type(4))) float;   // 4 fp32 acc

#define B_ROWS 4096
#define NTOT   8192
#define DD     128
#define SQRTC1 1.6986436f            // sqrt(2*log2(e)) — pre-scale so MFMA yields C1*dot
#define E2f    7.389056098930650f    // exp(2): diagonal term (self-dot) to subtract
#define LN2f   0.6931471805599453f   // 2p = d' * ln2  (d' = C1 * p)

// async global->LDS DMA, 16B per lane; LDS dest must be wave-uniform base + lane*16
#define GLOAD_LDS16(gptr, lptr)                                                          \
    __builtin_amdgcn_global_load_lds((const __attribute__((address_space(1))) void*)(gptr), \
                                     (__attribute__((address_space(3))) void*)(lptr), 16, 0, 0)

// ---------------- kernel 1: L2-normalize rows, scale by sqrt(C1), cast bf16 ----------------
__global__ __launch_bounds__(256) void nrm_kernel(const float* __restrict__ zi,
                                                  const float* __restrict__ zj,
                                                  __hip_bfloat16* __restrict__ zb) {
    int tid  = threadIdx.x;
    int wave = tid >> 6, lane = tid & 63;
    int row  = blockIdx.x * 4 + wave;
    const float* src = (row < B_ROWS) ? (zi + (size_t)row * DD)
                                      : (zj + (size_t)(row - B_ROWS) * DD);
    float2 v = *(const float2*)(src + lane * 2);
    float s = v.x * v.x + v.y * v.y;
    #pragma unroll
    for (int m = 1; m <= 32; m <<= 1) s += __shfl_xor(s, m, 64);
    float scale = SQRTC1 / fmaxf(sqrtf(s), 1e-12f);
    __hip_bfloat16* dst = zb + (size_t)row * DD + lane * 2;
    dst[0] = __float2bfloat16(v.x * scale);
    dst[1] = __float2bfloat16(v.y * scale);
}

// ---------------- kernel 2: fused sim-GEMM + partial sum of exp2 ----------------
// grid (32 row-tiles, 32 col-splits); block 256 = 4 waves. Block tile 256x256.
// Wave w: rows [r0+w*64, +64) as 4 row-fragments, full K=128 resident (64 VGPRs).
// B tiles (64 cols) DMA'd to LDS via global_load_lds, double-buffered, 1 barrier/tile.
// LDS chunk layout [kc8][col]: chunk c holds cols (c&63), k-bytes [(c>>6)*16, +16).
__global__ __launch_bounds__(256, 4) void sim_kernel(const __hip_bfloat16* __restrict__ zbf,
                                                     float* __restrict__ lpart) {
    __shared__ uint4 ldsB[2][1024];     // 2 x 16 KB
    const short* zs = (const short*)zbf;

    int tid = threadIdx.x;
    int w   = tid >> 6, lane = tid & 63;
    int q   = lane >> 4, n16 = lane & 15;
    int r0  = blockIdx.x * 256 + w * 64;
    int cq  = blockIdx.y;

    // A fragments: rows r0+rs*16+n16, k-chunk kc: m = lane&15, k = (lane>>4)*8 + j
    short8 af[4][4];
    #pragma unroll
    for (int rs = 0; rs < 4; ++rs) {
        const short* ap = zs + (size_t)(r0 + rs * 16 + n16) * DD + q * 8;
        #pragma unroll
        for (int kc = 0; kc < 4; ++kc)
            af[rs][kc] = *(const short8*)(ap + kc * 32);
    }

    // staging: thread owns chunks c = tid + 256*rr; global addr = (j0 + (c&63))*128 + (c>>6)*8
    int scol = tid & 63, skc8 = tid >> 6;
    const short* gcol = zs + (size_t)(cq * 256 + scol) * DD + skc8 * 8;

    float l[4][4];
    #pragma unroll
    for (int rs = 0; rs < 4; ++rs)
        #pragma unroll
        for (int r = 0; r < 4; ++r) l[rs][r] = 0.f;

    // prologue: stage tile 0 into buf 0
    #pragma unroll
    for (int rr = 0; rr < 4; ++rr)
        GLOAD_LDS16(gcol + rr * 32, &ldsB[0][tid + 256 * rr]);
    __syncthreads();   // compiler drains vmcnt before s_barrier

    #pragma unroll
    for (int t = 0; t < 4; ++t) {
        // issue next tile's DMA into the other buffer (overlaps with compute below)
        if (t < 3) {
            const short* gn = gcol + (size_t)(t + 1) * 64 * DD;
            #pragma unroll
            for (int rr = 0; rr < 4; ++rr)
                GLOAD_LDS16(gn + rr * 32, &ldsB[(t + 1) & 1][tid + 256 * rr]);
        }
        const uint4* Lb = ldsB[t & 1];
        #pragma unroll
        for (int st = 0; st < 4; ++st) {
            floatx4 acc[4];
            #pragma unroll
            for (int rs = 0; rs < 4; ++rs) acc[rs] = (floatx4){0.f, 0.f, 0.f, 0.f};
            #pragma unroll
            for (int kc = 0; kc < 4; ++kc) {
                // B frag: col = st*16+n16, k-chunk16B = kc*4+q  ->  chunk = (kc*4+q)*64 + col
                short8 bf = *(const short8*)&Lb[(kc * 4 + q) * 64 + st * 16 + n16];
                #pragma unroll
                for (int rs = 0; rs < 4; ++rs)
                    acc[rs] = __builtin_amdgcn_mfma_f32_16x16x32_bf16(af[rs][kc], bf, acc[rs], 0, 0, 0);
            }
            // epilogue: exp2 + add per element (C layout: row = q*4+r, col = n16)
            #pragma unroll
            for (int rs = 0; rs < 4; ++rs)
                #pragma unroll
                for (int r = 0; r < 4; ++r)
                    l[rs][r] += __builtin_amdgcn_exp2f(acc[rs][r]);
        }
        __syncthreads();   // drains next tile's DMA + releases this buffer
    }

    // reduce the 16 column-lanes (lanes sharing q hold the same 4 rows)
    #pragma unroll
    for (int rs = 0; rs < 4; ++rs)
        #pragma unroll
        for (int r = 0; r < 4; ++r) {
            float v = l[rs][r];
            v += __shfl_xor(v, 1, 64);
            v += __shfl_xor(v, 2, 64);
            v += __shfl_xor(v, 4, 64);
            v += __shfl_xor(v, 8, 64);
            l[rs][r] = v;
        }
    if (n16 == 0) {
        #pragma unroll
        for (int rs = 0; rs < 4; ++rs)
            #pragma unroll
            for (int r = 0; r < 4; ++r) {
                int row = r0 + rs * 16 + q * 4 + r;
                lpart[row * 32 + cq] = l[rs][r];
            }
    }
}

// ---------------- kernel 3: finalize ----------------
// loss_i = -d'*ln2 + ln(sum_exp2 - e^2); mean via block reduce + 32 atomics
__global__ __launch_bounds__(256) void fin_kernel(const __hip_bfloat16* __restrict__ zbf,
                                                  const float* __restrict__ lpart,
                                                  float* __restrict__ out) {
    __shared__ float red[256];
    int row = blockIdx.x * 256 + threadIdx.x;

    const float4* lp = (const float4*)(lpart + row * 32);
    float l = 0.f;
    #pragma unroll
    for (int i = 0; i < 8; ++i) { float4 v = lp[i]; l += (v.x + v.y) + (v.z + v.w); }

    const __hip_bfloat162* a = (const __hip_bfloat162*)(zbf + (size_t)row * DD);
    const __hip_bfloat162* b = (const __hip_bfloat162*)(zbf + (size_t)(row ^ B_ROWS) * DD);
    float d = 0.f;
    #pragma unroll
    for (int i = 0; i < 64; ++i) {
        float2 av = __bfloat1622float2(a[i]);
        float2 bv = __bfloat1622float2(b[i]);
        d += av.x * bv.x + av.y * bv.y;
    }

    float loss = -d * LN2f + logf(l - E2f);
    red[threadIdx.x] = loss;
    __syncthreads();
    #pragma unroll
    for (int s = 128; s > 0; s >>= 1) {
        if (threadIdx.x < s) red[threadIdx.x] += red[threadIdx.x + s];
        __syncthreads();
    }
    if (threadIdx.x == 0) atomicAdd(out, red[0] * (1.0f / (float)NTOT));
}

extern "C" void kernel_launch(void* const* d_in, const int* in_sizes, int n_in,
                              void* d_out, int out_size, void* d_ws, size_t ws_size,
                              hipStream_t stream) {
    const float* zi = (const float*)d_in[0];
    const float* zj = (const float*)d_in[1];
    float* out = (float*)d_out;

    __hip_bfloat16* zb = (__hip_bfloat16*)d_ws;                         // 2 MB
    float* lpart = (float*)((char*)d_ws + (size_t)NTOT * DD * 2);       // 1 MB (8192 x 32)

    hipMemsetAsync(d_out, 0, sizeof(float), stream);
    nrm_kernel<<<NTOT / 4, 256, 0, stream>>>(zi, zj, zb);
    sim_kernel<<<dim3(32, 32), 256, 0, stream>>>(zb, lpart);
    fin_kernel<<<NTOT / 256, 256, 0, stream>>>(zb, lpart, out);
}